// Round 1
// 376.299 us; speedup vs baseline: 1.1079x; 1.1079x over previous
//
#include <hip/hip_runtime.h>
#include <hip/hip_bf16.h>

// AlignmentContrastiveLoss on MI355X.
// Pipeline:
//   K1 normalize_pack: fp32 L2-normalize rows of im_set/s_seq, drop CLS/special
//      tokens, cast to bf16, write zero-padded im' [256][48][1024], s' [256][32][1024].
//   K2 gemm_scores: bf16 MFMA GEMM (M=96 rows = 2 images x 48, N=256 cols = 8
//      sentences x 32, K=1024) with fused masked max-over-regions /
//      sum-over-words epilogue -> scores[256][256] fp32.
//      Staging: global_load_lds_dwordx4 DMA into LINEAR stride-64 LDS with an
//      XOR chunk-swizzle applied on the (per-lane) global source address and on
//      the ds_read side (both-sides rule) -> no VGPR round-trip, no staging
//      address VALU, bank-uniform access.
//   K3 loss_kernel: contrastive loss with hardest negatives -> scalar.

typedef __attribute__((ext_vector_type(8))) short bf16x8;
typedef __attribute__((ext_vector_type(4))) float f32x4;

#define NB   256
#define DIM  1024
#define LI   36     // valid image regions after dropping CLS
#define LIP  48     // padded to 3 x 16
#define LS   30     // valid words after dropping first + last two
#define LSP  32     // padded to 2 x 16

static __device__ inline ushort f2bf(float x) {
    union { __hip_bfloat16 h; ushort u; } cvt;
    cvt.h = __float2bfloat16(x);
    return cvt.u;
}

// Async global->LDS DMA, 16B per lane. LDS dest is wave-uniform base + lane*16
// (linear); global source is per-lane (carries the swizzle).
static __device__ __forceinline__ void gload_lds16(const void* g, void* l) {
    __builtin_amdgcn_global_load_lds(
        (const __attribute__((address_space(1))) void*)g,
        (__attribute__((address_space(3))) void*)l, 16, 0, 0);
}

// One wave per output row. Rows 0..256*48-1 -> im', rest -> s'.
__global__ __launch_bounds__(256) void normalize_pack(
    const float* __restrict__ im, const float* __restrict__ sq,
    short* __restrict__ imp, short* __restrict__ sp)
{
    const int gw   = (blockIdx.x * 256 + threadIdx.x) >> 6;
    const int lane = threadIdx.x & 63;
    const int NIM  = NB * LIP;

    const float* src = nullptr;
    short* dst;
    if (gw < NIM) {
        int b = gw / LIP, i = gw - b * LIP;
        dst = imp + (size_t)gw * DIM;
        if (i < LI) src = im + ((size_t)b * 37 + i + 1) * DIM;   // drop CLS region 0
    } else {
        int g2 = gw - NIM;
        int b = g2 / LSP, j = g2 - b * LSP;
        dst = sp + (size_t)g2 * DIM;
        if (j < LS) src = sq + ((size_t)b * 33 + j + 1) * DIM;   // rows 1..30 of 33
    }

    if (src) {
        const float4* s4 = (const float4*)src;
        float4 v[4];
        float ss = 0.f;
        #pragma unroll
        for (int t = 0; t < 4; ++t) {
            float4 x = s4[lane + 64 * t];
            v[t] = x;
            ss += x.x * x.x + x.y * x.y + x.z * x.z + x.w * x.w;
        }
        #pragma unroll
        for (int o = 32; o >= 1; o >>= 1) ss += __shfl_xor(ss, o, 64);
        float scale = 1.0f / fmaxf(sqrtf(ss), 1e-12f);
        ushort4* d4 = (ushort4*)dst;
        #pragma unroll
        for (int t = 0; t < 4; ++t) {
            float4 x = v[t];
            ushort4 o;
            o.x = f2bf(x.x * scale);
            o.y = f2bf(x.y * scale);
            o.z = f2bf(x.z * scale);
            o.w = f2bf(x.w * scale);
            d4[lane + 64 * t] = o;
        }
    } else {
        // padding row: zero it (ws is re-poisoned before every launch)
        uint4 z = {0u, 0u, 0u, 0u};
        uint4* d4 = (uint4*)dst;   // 1024 bf16 = 128 uint4
        d4[lane] = z;
        d4[lane + 64] = z;
    }
}

// Block: 256 threads = 4 waves. blockIdx.x -> pair of images (b0=2*x),
// blockIdx.y -> 8 sentences (c0=8*y). Wave w owns N-tiles 4w..4w+3
// (= sentences c0+2w, c0+2w+1), all 6 M-tiles -> its 4 score cells are
// wave-private.
//
// LDS layout: linear rows of 64 bf16 (128 B), XOR-swizzled in 16B chunks:
//   physical_chunk = logical_chunk ^ (row & 7)
// Staging (8 rows / 1 KB per global_load_lds): lane i writes LDS byte
// base + i*16 = row (r0 + i>>3), chunk (i&7); its global source must be
// logical chunk (i&7)^(row&7) = (i&7)^(i>>3)  [r0 is a multiple of 8].
// Reads: every MFMA tile row base is a multiple of 16, so row&7 = l15&7 and
// the read-side chunk is (g*4+q)^(l15&7) -- a per-lane constant.
__global__ __launch_bounds__(256) void gemm_scores(
    const short* __restrict__ imp, const short* __restrict__ sp,
    const int* __restrict__ im_len, const int* __restrict__ s_len,
    float* __restrict__ scores)
{
    __shared__ short As[96 * 64];    // 12 KB
    __shared__ short Bs[256 * 64];   // 32 KB

    const int tid  = threadIdx.x;
    const int wave = tid >> 6;
    const int lane = tid & 63;
    const int q    = lane >> 4;
    const int l15  = lane & 15;
    const int b0   = blockIdx.x * 2;
    const int c0   = blockIdx.y * 8;

    f32x4 acc[6][4];
    #pragma unroll
    for (int mt = 0; mt < 6; ++mt)
        #pragma unroll
        for (int t = 0; t < 4; ++t)
            acc[mt][t] = (f32x4){0.f, 0.f, 0.f, 0.f};

    // Per-lane staging source constants (see header comment).
    const int srow   = lane >> 3;             // row within the 8-row block
    const int schunk = (lane & 7) ^ srow;     // inverse-swizzled 16B chunk
    const char* gA = (const char*)imp + (size_t)(b0 * LIP) * (DIM * 2)
                     + srow * (DIM * 2) + schunk * 16;
    const char* gB = (const char*)sp + (size_t)(c0 * LSP) * (DIM * 2)
                     + srow * (DIM * 2) + schunk * 16;

    // Read-side swizzled chunk byte offsets (constant over the K loop).
    const int cs0 = (q ^ (l15 & 7)) * 16;          // g = 0
    const int cs1 = ((4 + q) ^ (l15 & 7)) * 16;    // g = 1

    const int wa3 = wave * 3;   // A row-blocks 3/wave (12 total)
    const int wb8 = wave * 8;   // B row-blocks 8/wave (32 total)

    for (int k0 = 0; k0 < DIM; k0 += 64) {
        const int kb = k0 * 2;   // byte offset of this K-slice within a row
        // stage A: 96 rows x 128 B = 12 KB = 12 DMA instrs, 3/wave
        #pragma unroll
        for (int it = 0; it < 3; ++it) {
            const int rb = wa3 + it;
            gload_lds16(gA + rb * (8 * DIM * 2) + kb, (char*)As + rb * 1024);
        }
        // stage B: 256 rows x 128 B = 32 KB = 32 DMA instrs, 8/wave
        #pragma unroll
        for (int it = 0; it < 8; ++it) {
            const int rb = wb8 + it;
            gload_lds16(gB + rb * (8 * DIM * 2) + kb, (char*)Bs + rb * 1024);
        }
        __syncthreads();   // compiler emits vmcnt(0) drain for the DMA
        #pragma unroll
        for (int g = 0; g < 2; ++g) {
            const int cs = g ? cs1 : cs0;
            bf16x8 af[6], bfr[4];
            #pragma unroll
            for (int mt = 0; mt < 6; ++mt)
                af[mt] = *(const bf16x8*)((const char*)As + (mt * 16 + l15) * 128 + cs);
            #pragma unroll
            for (int t = 0; t < 4; ++t)
                bfr[t] = *(const bf16x8*)((const char*)Bs + ((wave * 4 + t) * 16 + l15) * 128 + cs);
            #pragma unroll
            for (int mt = 0; mt < 6; ++mt)
                #pragma unroll
                for (int t = 0; t < 4; ++t)
                    acc[mt][t] = __builtin_amdgcn_mfma_f32_16x16x32_bf16(
                        af[mt], bfr[t], acc[mt][t], 0, 0, 0);
        }
        __syncthreads();
    }

    // Fused epilogue. C/D layout: lane holds col = lane&15, row = (lane>>4)*4 + r.
    const int iml0 = im_len[b0] - 1;       // in [9, 36]
    const int iml1 = im_len[b0 + 1] - 1;

    float sc[2][2] = {{0.f, 0.f}, {0.f, 0.f}};
    #pragma unroll
    for (int t = 0; t < 4; ++t) {
        const int nt = wave * 4 + t;
        const int c  = c0 + (nt >> 1);
        const int sl = s_len[c] - 3;                 // valid words, in [5, 30]
        const int jj = (nt & 1) * 16 + l15;          // word index within sentence
        const bool jv = (jj < sl);
        #pragma unroll
        for (int bb = 0; bb < 2; ++bb) {
            const int il = bb ? iml1 : iml0;
            float m = -3.4e38f;
            #pragma unroll
            for (int mt3 = 0; mt3 < 3; ++mt3) {
                #pragma unroll
                for (int r = 0; r < 4; ++r) {
                    int i = mt3 * 16 + q * 4 + r;    // global region index
                    float v = acc[bb * 3 + mt3][t][r];
                    if (i < il) m = fmaxf(m, v);     // pads & masked rows excluded
                }
            }
            // combine the 4 row-quads -> full max over i for column l15
            m = fmaxf(m, __shfl_xor(m, 16, 64));
            m = fmaxf(m, __shfl_xor(m, 32, 64));
            // reference: masked entries are 0 and participate in the max only
            // when some region is masked (il < 36)
            if (il < LI) m = fmaxf(m, 0.f);
            float v = (q == 0 && jv) ? m : 0.f;      // count each column once
            #pragma unroll
            for (int off = 32; off >= 1; off >>= 1) v += __shfl_xor(v, off, 64);
            sc[bb][t >> 1] += v;
        }
    }
    if (lane == 0) {
        #pragma unroll
        for (int bb = 0; bb < 2; ++bb)
            #pragma unroll
            for (int h = 0; h < 2; ++h)
                scores[(b0 + bb) * NB + c0 + wave * 2 + h] = sc[bb][h];
    }
}

// cost_s[t] = max_{c!=t} relu(M + s[t][c] - s[t][t]);
// cost_im[t] = max_{b!=t} relu(M + s[b][t] - s[t][t]); loss = sum of both.
__global__ __launch_bounds__(256) void loss_kernel(
    const float* __restrict__ sc, float* __restrict__ out)
{
    const int t = threadIdx.x;
    const float dt = sc[t * (NB + 1)];
    float rowmax = 0.f, colmax = 0.f;
    for (int k = 0; k < NB; ++k) {
        if (k != t) {
            rowmax = fmaxf(rowmax, 0.2f + sc[t * NB + k] - dt);
            colmax = fmaxf(colmax, 0.2f + sc[k * NB + t] - dt);
        }
    }
    rowmax = fmaxf(rowmax, 0.f);   // relu == max with the zeroed diagonal
    colmax = fmaxf(colmax, 0.f);
    float v = rowmax + colmax;
    __shared__ float red[4];
    #pragma unroll
    for (int o = 32; o >= 1; o >>= 1) v += __shfl_xor(v, o, 64);
    if ((t & 63) == 0) red[t >> 6] = v;
    __syncthreads();
    if (t == 0) out[0] = red[0] + red[1] + red[2] + red[3];
}

extern "C" void kernel_launch(void* const* d_in, const int* in_sizes, int n_in,
                              void* d_out, int out_size, void* d_ws, size_t ws_size,
                              hipStream_t stream) {
    const float* im_set = (const float*)d_in[0];
    const float* s_seq  = (const float*)d_in[1];
    const int*   im_len = (const int*)d_in[2];
    const int*   s_len  = (const int*)d_in[3];
    float* out = (float*)d_out;

    char* ws = (char*)d_ws;
    const size_t imp_bytes = (size_t)NB * LIP * DIM * 2;   // 25.2 MB
    const size_t sp_bytes  = (size_t)NB * LSP * DIM * 2;   // 16.8 MB
    short* imp    = (short*)ws;
    short* sp     = (short*)(ws + imp_bytes);
    float* scores = (float*)(ws + imp_bytes + sp_bytes);   // 256 KB

    // 256*48 + 256*32 = 20480 rows, one wave each -> 5120 blocks
    normalize_pack<<<5120, 256, 0, stream>>>(im_set, s_seq, imp, sp);

    dim3 grid(NB / 2, NB / 8);
    gemm_scores<<<grid, 256, 0, stream>>>(imp, sp, im_len, s_len, scores);

    loss_kernel<<<1, 256, 0, stream>>>(scores, out);
}

// Round 2
// 305.131 us; speedup vs baseline: 1.3664x; 1.2332x over previous
//
#include <hip/hip_runtime.h>
#include <hip/hip_bf16.h>

// AlignmentContrastiveLoss on MI355X.
// Pipeline:
//   K1 normalize_pack: fp32 L2-normalize rows of im_set/s_seq, drop CLS/special
//      tokens, cast to bf16. im' is DENSELY packed: [256 images][36 rows][1024]
//      (no pad rows; 4 images = 144 rows = 9 MFMA tiles). s' stays [256][32][1024]
//      zero-padded (30 valid words).
//   K2 gemm_scores: bf16 MFMA GEMM per block: M=144 rows (4 images x 36),
//      N=256 cols (8 sentences x 32), K=1024, fused masked max-over-regions /
//      sum-over-words epilogue -> scores[256][256] fp32.
//      Staging: global_load_lds_dwordx4 DMA into LINEAR stride-64 LDS with an
//      XOR chunk-swizzle applied on the (per-lane) global source address and on
//      the ds_read side (both-sides rule).
//   K3 loss_kernel: contrastive loss with hardest negatives -> scalar.

typedef __attribute__((ext_vector_type(8))) short bf16x8;
typedef __attribute__((ext_vector_type(4))) float f32x4;

#define NB   256
#define DIM  1024
#define LI   36     // valid image regions after dropping CLS (dense pack stride)
#define LS   30     // valid words after dropping first + last two
#define LSP  32     // padded to 2 x 16
#define MT   9      // M-tiles per block (144 rows)

static __device__ inline ushort f2bf(float x) {
    union { __hip_bfloat16 h; ushort u; } cvt;
    cvt.h = __float2bfloat16(x);
    return cvt.u;
}

// Async global->LDS DMA, 16B per lane. LDS dest is wave-uniform base + lane*16
// (linear); global source is per-lane (carries the swizzle).
static __device__ __forceinline__ void gload_lds16(const void* g, void* l) {
    __builtin_amdgcn_global_load_lds(
        (const __attribute__((address_space(1))) void*)g,
        (__attribute__((address_space(3))) void*)l, 16, 0, 0);
}

// One wave per output row. Rows 0..256*36-1 -> im' (dense), rest -> s'.
__global__ __launch_bounds__(256) void normalize_pack(
    const float* __restrict__ im, const float* __restrict__ sq,
    short* __restrict__ imp, short* __restrict__ sp)
{
    const int gw   = (blockIdx.x * 256 + threadIdx.x) >> 6;
    const int lane = threadIdx.x & 63;
    const int NIM  = NB * LI;   // 9216 dense image rows

    const float* src = nullptr;
    short* dst;
    if (gw < NIM) {
        int b = gw / LI, i = gw - b * LI;
        dst = imp + (size_t)gw * DIM;
        src = im + ((size_t)b * 37 + i + 1) * DIM;   // drop CLS region 0
    } else {
        int g2 = gw - NIM;
        int b = g2 >> 5, j = g2 & 31;
        dst = sp + (size_t)g2 * DIM;
        if (j < LS) src = sq + ((size_t)b * 33 + j + 1) * DIM;   // rows 1..30 of 33
    }

    if (src) {
        const float4* s4 = (const float4*)src;
        float4 v[4];
        float ss = 0.f;
        #pragma unroll
        for (int t = 0; t < 4; ++t) {
            float4 x = s4[lane + 64 * t];
            v[t] = x;
            ss += x.x * x.x + x.y * x.y + x.z * x.z + x.w * x.w;
        }
        #pragma unroll
        for (int o = 32; o >= 1; o >>= 1) ss += __shfl_xor(ss, o, 64);
        float scale = 1.0f / fmaxf(sqrtf(ss), 1e-12f);
        ushort4* d4 = (ushort4*)dst;
        #pragma unroll
        for (int t = 0; t < 4; ++t) {
            float4 x = v[t];
            ushort4 o;
            o.x = f2bf(x.x * scale);
            o.y = f2bf(x.y * scale);
            o.z = f2bf(x.z * scale);
            o.w = f2bf(x.w * scale);
            d4[lane + 64 * t] = o;
        }
    } else {
        // sentence padding row: zero it (ws is re-poisoned before every launch)
        uint4 z = {0u, 0u, 0u, 0u};
        uint4* d4 = (uint4*)dst;   // 1024 bf16 = 128 uint4
        d4[lane] = z;
        d4[lane + 64] = z;
    }
}

// Block: 256 threads = 4 waves. blockIdx.x -> 4 images (b0=4*x, rows densely
// packed: 144 = 9 x 16). blockIdx.y -> 8 sentences (c0=8*y). Wave w owns
// N-tiles 4w..4w+3 (= sentences c0+2w, c0+2w+1), all 9 M-tiles -> its score
// cells are wave-private.
//
// LDS layout: linear rows of 64 bf16 (128 B), XOR-swizzled in 16B chunks:
//   physical_chunk = logical_chunk ^ (row & 7)
// Staging (8 rows / 1 KB per global_load_lds): lane i writes LDS byte
// base + i*16 = row (r0 + i>>3), chunk (i&7); its global source is logical
// chunk (i&7)^(i>>3)  [r0 multiple of 8; block row bases are multiples of 16].
// Reads: MFMA tile row base is a multiple of 16, so row&7 = l15&7 and the
// read-side chunk is (g*4+q)^(l15&7) -- a per-lane constant.
__global__ __launch_bounds__(256, 2) void gemm_scores(
    const short* __restrict__ imp, const short* __restrict__ sp,
    const int* __restrict__ im_len, const int* __restrict__ s_len,
    float* __restrict__ scores)
{
    __shared__ short As[144 * 64];   // 18 KB
    __shared__ short Bs[256 * 64];   // 32 KB

    const int tid  = threadIdx.x;
    const int wave = tid >> 6;
    const int lane = tid & 63;
    const int q    = lane >> 4;
    const int l15  = lane & 15;
    const int b0   = blockIdx.x * 4;
    const int c0   = blockIdx.y * 8;

    f32x4 acc[MT][4];
    #pragma unroll
    for (int mt = 0; mt < MT; ++mt)
        #pragma unroll
        for (int t = 0; t < 4; ++t)
            acc[mt][t] = (f32x4){0.f, 0.f, 0.f, 0.f};

    // Per-lane staging source constants (see header comment).
    const int srow   = lane >> 3;             // row within the 8-row block
    const int schunk = (lane & 7) ^ srow;     // inverse-swizzled 16B chunk
    const char* gA = (const char*)imp + (size_t)(b0 * LI) * (DIM * 2)
                     + srow * (DIM * 2) + schunk * 16;
    const char* gB = (const char*)sp + (size_t)(c0 * LSP) * (DIM * 2)
                     + srow * (DIM * 2) + schunk * 16;

    // Read-side swizzled chunk byte offsets (constant over the K loop).
    const int cs0 = (q ^ (l15 & 7)) * 16;          // g = 0
    const int cs1 = ((4 + q) ^ (l15 & 7)) * 16;    // g = 1

    const int wa4 = wave * 4;   // A row-blocks: 18 total, 4/wave + 2 extra
    const int wb8 = wave * 8;   // B row-blocks: 32 total, 8/wave

    for (int k0 = 0; k0 < DIM; k0 += 64) {
        const int kb = k0 * 2;   // byte offset of this K-slice within a row
        // stage A: 144 rows x 128 B = 18 KB = 18 DMA instrs
        #pragma unroll
        for (int it = 0; it < 4; ++it) {
            const int rb = wa4 + it;
            gload_lds16(gA + rb * (8 * DIM * 2) + kb, (char*)As + rb * 1024);
        }
        if (wave < 2) {
            const int rb = 16 + wave;
            gload_lds16(gA + rb * (8 * DIM * 2) + kb, (char*)As + rb * 1024);
        }
        // stage B: 256 rows x 128 B = 32 KB = 32 DMA instrs, 8/wave
        #pragma unroll
        for (int it = 0; it < 8; ++it) {
            const int rb = wb8 + it;
            gload_lds16(gB + rb * (8 * DIM * 2) + kb, (char*)Bs + rb * 1024);
        }
        __syncthreads();   // compiler emits vmcnt(0) drain for the DMA
        #pragma unroll
        for (int g = 0; g < 2; ++g) {
            const int cs = g ? cs1 : cs0;
            bf16x8 af[MT], bfr[4];
            #pragma unroll
            for (int mt = 0; mt < MT; ++mt)
                af[mt] = *(const bf16x8*)((const char*)As + (mt * 16 + l15) * 128 + cs);
            #pragma unroll
            for (int t = 0; t < 4; ++t)
                bfr[t] = *(const bf16x8*)((const char*)Bs + ((wave * 4 + t) * 16 + l15) * 128 + cs);
            #pragma unroll
            for (int mt = 0; mt < MT; ++mt)
                #pragma unroll
                for (int t = 0; t < 4; ++t)
                    acc[mt][t] = __builtin_amdgcn_mfma_f32_16x16x32_bf16(
                        af[mt], bfr[t], acc[mt][t], 0, 0, 0);
        }
        __syncthreads();
    }

    // Fused epilogue. C/D layout: lane holds col = lane&15, row = (lane>>4)*4 + r.
    // Packed global row g = mt*16 + q*4 + r; image = g/36 = (4*mt+q)/9 (exact
    // since 36 = 4*9 and r < 4 -- image boundaries fall on q-quad boundaries),
    // region i = g - 36*image.
    int il[4];
    #pragma unroll
    for (int bb = 0; bb < 4; ++bb) il[bb] = im_len[b0 + bb] - 1;   // in [9, 36]

    float sc[4][2] = {{0.f, 0.f}, {0.f, 0.f}, {0.f, 0.f}, {0.f, 0.f}};
    #pragma unroll
    for (int t = 0; t < 4; ++t) {
        const int nt = wave * 4 + t;
        const int c  = c0 + (nt >> 1);
        const int sl = s_len[c] - 3;                 // valid words, in [5, 30]
        const int jj = (nt & 1) * 16 + l15;          // word index within sentence
        const bool jv = (jj < sl);

        float m[4] = {-3.4e38f, -3.4e38f, -3.4e38f, -3.4e38f};
        #pragma unroll
        for (int mt = 0; mt < MT; ++mt) {
            const int im_lo = (4 * mt) / 9;          // compile-time
            const int im_hi = (4 * mt + 3) / 9;      // compile-time
            const int thr   = 9 * im_hi - 4 * mt;    // q >= thr -> im_hi
            #pragma unroll
            for (int r = 0; r < 4; ++r) {
                const float v = acc[mt][t][r];
                const int base = mt * 16 + q * 4 + r;
                if (im_lo == im_hi) {
                    const int i = base - 36 * im_lo;
                    if (i < il[im_lo]) m[im_lo] = fmaxf(m[im_lo], v);
                } else {
                    const bool hi = (q >= thr);
                    if (!hi) {
                        const int i = base - 36 * im_lo;
                        if (i < il[im_lo]) m[im_lo] = fmaxf(m[im_lo], v);
                    } else {
                        const int i = base - 36 * im_hi;
                        if (i < il[im_hi]) m[im_hi] = fmaxf(m[im_hi], v);
                    }
                }
            }
        }
        #pragma unroll
        for (int bb = 0; bb < 4; ++bb) {
            float mm = m[bb];
            // combine the 4 row-quads -> full max over this image's regions
            mm = fmaxf(mm, __shfl_xor(mm, 16, 64));
            mm = fmaxf(mm, __shfl_xor(mm, 32, 64));
            // reference: masked entries are 0 and participate in the max only
            // when some region is masked (il < 36)
            if (il[bb] < LI) mm = fmaxf(mm, 0.f);
            float v = (q == 0 && jv) ? mm : 0.f;     // count each column once
            #pragma unroll
            for (int off = 32; off >= 1; off >>= 1) v += __shfl_xor(v, off, 64);
            sc[bb][t >> 1] += v;
        }
    }
    if (lane == 0) {
        #pragma unroll
        for (int bb = 0; bb < 4; ++bb)
            #pragma unroll
            for (int h = 0; h < 2; ++h)
                scores[(b0 + bb) * NB + c0 + wave * 2 + h] = sc[bb][h];
    }
}

// cost_s[t] = max_{c!=t} relu(M + s[t][c] - s[t][t]);
// cost_im[t] = max_{b!=t} relu(M + s[b][t] - s[t][t]); loss = sum of both.
__global__ __launch_bounds__(256) void loss_kernel(
    const float* __restrict__ sc, float* __restrict__ out)
{
    const int t = threadIdx.x;
    const float dt = sc[t * (NB + 1)];
    float rowmax = 0.f, colmax = 0.f;
    for (int k = 0; k < NB; ++k) {
        if (k != t) {
            rowmax = fmaxf(rowmax, 0.2f + sc[t * NB + k] - dt);
            colmax = fmaxf(colmax, 0.2f + sc[k * NB + t] - dt);
        }
    }
    rowmax = fmaxf(rowmax, 0.f);   // relu == max with the zeroed diagonal
    colmax = fmaxf(colmax, 0.f);
    float v = rowmax + colmax;
    __shared__ float red[4];
    #pragma unroll
    for (int o = 32; o >= 1; o >>= 1) v += __shfl_xor(v, o, 64);
    if ((t & 63) == 0) red[t >> 6] = v;
    __syncthreads();
    if (t == 0) out[0] = red[0] + red[1] + red[2] + red[3];
}

extern "C" void kernel_launch(void* const* d_in, const int* in_sizes, int n_in,
                              void* d_out, int out_size, void* d_ws, size_t ws_size,
                              hipStream_t stream) {
    const float* im_set = (const float*)d_in[0];
    const float* s_seq  = (const float*)d_in[1];
    const int*   im_len = (const int*)d_in[2];
    const int*   s_len  = (const int*)d_in[3];
    float* out = (float*)d_out;

    char* ws = (char*)d_ws;
    const size_t imp_bytes = (size_t)NB * LI * DIM * 2;    // 18.9 MB (dense)
    const size_t sp_bytes  = (size_t)NB * LSP * DIM * 2;   // 16.8 MB
    short* imp    = (short*)ws;
    short* sp     = (short*)(ws + imp_bytes);
    float* scores = (float*)(ws + imp_bytes + sp_bytes);   // 256 KB

    // 256*36 + 256*32 = 17408 rows, one wave each -> 4352 blocks
    normalize_pack<<<4352, 256, 0, stream>>>(im_set, s_seq, imp, sp);

    dim3 grid(NB / 4, NB / 8);
    gemm_scores<<<grid, 256, 0, stream>>>(imp, sp, im_len, s_len, scores);

    loss_kernel<<<1, 256, 0, stream>>>(scores, out);
}

// Round 3
// 260.557 us; speedup vs baseline: 1.6001x; 1.1711x over previous
//
#include <hip/hip_runtime.h>
#include <hip/hip_bf16.h>

// AlignmentContrastiveLoss on MI355X.
// Pipeline:
//   K1 normalize_pack: fp32 L2-normalize rows of im_set/s_seq, drop CLS/special
//      tokens, cast to bf16. Both packed DENSE: im' [256][36][1024],
//      s' [256][30][1024] (no pad rows at all).
//   K2 gemm_scores: bf16 MFMA GEMM per block: M=144 (4 images x 36),
//      N=240 (8 sentences x 30, 15 tiles), K=1024, 8 waves (512 thr), fused
//      masked max-over-regions / sum-over-words epilogue -> scores[256][256].
//      Staging: global_load_lds_dwordx4 DMA into LINEAR stride-64 LDS with XOR
//      chunk-swizzle on the per-lane global source + swizzled ds_read.
//      8 waves x 2 N-tiles/wave keeps acc at 72 regs -> 128-reg cap ->
//      16 waves/CU (2 blocks) for cross-wave pipe overlap.
//   K3 loss_partial + loss_final: contrastive loss, 64-block parallel.

typedef __attribute__((ext_vector_type(8))) short bf16x8;
typedef __attribute__((ext_vector_type(4))) float f32x4;

#define NB   256
#define DIM  1024
#define LI   36     // valid image regions (dense pack stride)
#define LS   30     // valid words (dense pack stride)
#define MT   9      // M-tiles per block (144 rows)
#define NT   15     // N-tiles per block (240 rows)

static __device__ inline ushort f2bf(float x) {
    union { __hip_bfloat16 h; ushort u; } cvt;
    cvt.h = __float2bfloat16(x);
    return cvt.u;
}

static __device__ __forceinline__ void gload_lds16(const void* g, void* l) {
    __builtin_amdgcn_global_load_lds(
        (const __attribute__((address_space(1))) void*)g,
        (__attribute__((address_space(3))) void*)l, 16, 0, 0);
}

// One wave per output row; every row is a real (valid) row now.
__global__ __launch_bounds__(256) void normalize_pack(
    const float* __restrict__ im, const float* __restrict__ sq,
    short* __restrict__ imp, short* __restrict__ sp)
{
    const int gw   = (blockIdx.x * 256 + threadIdx.x) >> 6;
    const int lane = threadIdx.x & 63;
    const int NIM  = NB * LI;   // 9216 dense image rows

    const float* src;
    short* dst;
    if (gw < NIM) {
        int b = gw / LI, i = gw - b * LI;
        dst = imp + (size_t)gw * DIM;
        src = im + ((size_t)b * 37 + i + 1) * DIM;   // drop CLS region 0
    } else {
        int g2 = gw - NIM;                            // 0 .. 7679
        int b = g2 / LS, j = g2 - b * LS;
        dst = sp + (size_t)g2 * DIM;
        src = sq + ((size_t)b * 33 + j + 1) * DIM;   // rows 1..30 of 33
    }

    const float4* s4 = (const float4*)src;
    float4 v[4];
    float ss = 0.f;
    #pragma unroll
    for (int t = 0; t < 4; ++t) {
        float4 x = s4[lane + 64 * t];
        v[t] = x;
        ss += x.x * x.x + x.y * x.y + x.z * x.z + x.w * x.w;
    }
    #pragma unroll
    for (int o = 32; o >= 1; o >>= 1) ss += __shfl_xor(ss, o, 64);
    float scale = 1.0f / fmaxf(sqrtf(ss), 1e-12f);
    ushort4* d4 = (ushort4*)dst;
    #pragma unroll
    for (int t = 0; t < 4; ++t) {
        float4 x = v[t];
        ushort4 o;
        o.x = f2bf(x.x * scale);
        o.y = f2bf(x.y * scale);
        o.z = f2bf(x.z * scale);
        o.w = f2bf(x.w * scale);
        d4[lane + 64 * t] = o;
    }
}

// Block: 512 threads = 8 waves. blockIdx.x -> 4 images (144 dense rows),
// blockIdx.y -> 8 sentences (240 dense rows, 15 N-tiles).
// Wave w owns N-tiles {2w, 2w+1} (wave 7: {14} only).
//
// LDS: linear rows of 64 bf16 (128 B), XOR chunk-swizzle
//   physical_chunk = logical_chunk ^ (row & 7)
// DMA stages 8 rows / 1 KB per instr: lane i -> row (i>>3), chunk (i&7);
// global source logical chunk = (i&7)^(i>>3). Read side: tile row bases are
// multiples of 16 -> row&7 = l15&7 -> chunk = (g*4+q)^(l15&7), per-lane const.
__global__ __launch_bounds__(512, 4) void gemm_scores(
    const short* __restrict__ imp, const short* __restrict__ sp,
    const int* __restrict__ im_len, const int* __restrict__ s_len,
    float* __restrict__ scores)
{
    __shared__ short As[144 * 64];   // 18 KB
    __shared__ short Bs[240 * 64];   // 30 KB
    __shared__ float sred[8][4][2];  // [wave][img][sent-slot]

    const int tid  = threadIdx.x;
    const int wave = tid >> 6;
    const int lane = tid & 63;
    const int q    = lane >> 4;
    const int l15  = lane & 15;
    const int b0   = blockIdx.x * 4;
    const int c0   = blockIdx.y * 8;

    const int nt0 = 2 * wave;
    const int nt1 = 2 * wave + 1;          // == 15 for wave 7 -> skipped

    f32x4 acc[MT][2];
    #pragma unroll
    for (int mt = 0; mt < MT; ++mt)
        #pragma unroll
        for (int t = 0; t < 2; ++t)
            acc[mt][t] = (f32x4){0.f, 0.f, 0.f, 0.f};

    // Per-lane staging source constants.
    const int srow   = lane >> 3;             // row within the 8-row block
    const int schunk = (lane & 7) ^ srow;     // inverse-swizzled 16B chunk
    const char* gA = (const char*)imp + (size_t)(b0 * LI) * (DIM * 2)
                     + srow * (DIM * 2) + schunk * 16;
    const char* gB = (const char*)sp + (size_t)(c0 * LS) * (DIM * 2)
                     + srow * (DIM * 2) + schunk * 16;

    // Read-side swizzled chunk byte offsets.
    const int cs0 = (q ^ (l15 & 7)) * 16;          // g = 0
    const int cs1 = ((4 + q) ^ (l15 & 7)) * 16;    // g = 1

    for (int k0 = 0; k0 < DIM; k0 += 64) {
        const int kb = k0 * 2;
        // stage A: 144 rows -> 18 chunks of 8 rows, interleaved over 8 waves
        #pragma unroll
        for (int it = 0; it < 3; ++it) {
            const int cid = it * 8 + wave;
            if (cid < 18)
                gload_lds16(gA + cid * (8 * DIM * 2) + kb, (char*)As + cid * 1024);
        }
        // stage B: 240 rows -> 30 chunks
        #pragma unroll
        for (int it = 0; it < 4; ++it) {
            const int cid = it * 8 + wave;
            if (cid < 30)
                gload_lds16(gB + cid * (8 * DIM * 2) + kb, (char*)Bs + cid * 1024);
        }
        __syncthreads();   // vmcnt(0) drain for the DMA
        #pragma unroll
        for (int g = 0; g < 2; ++g) {
            const int cs = g ? cs1 : cs0;
            bf16x8 b0f = *(const bf16x8*)((const char*)Bs + (nt0 * 16 + l15) * 128 + cs);
            bf16x8 b1f;
            if (nt1 < NT)
                b1f = *(const bf16x8*)((const char*)Bs + (nt1 * 16 + l15) * 128 + cs);
            #pragma unroll
            for (int mt = 0; mt < MT; ++mt) {
                bf16x8 af = *(const bf16x8*)((const char*)As + (mt * 16 + l15) * 128 + cs);
                acc[mt][0] = __builtin_amdgcn_mfma_f32_16x16x32_bf16(af, b0f, acc[mt][0], 0, 0, 0);
                if (nt1 < NT)
                    acc[mt][1] = __builtin_amdgcn_mfma_f32_16x16x32_bf16(af, b1f, acc[mt][1], 0, 0, 0);
            }
        }
        __syncthreads();
    }

    // ---- Fused epilogue ----
    // C/D layout: lane holds col = l15, row = q*4 + r.
    // Packed A row g = mt*16 + q*4 + r; image = (4*mt+q)/9, region i = g - 36*image.
    // Packed B col (within block) col = nt*16 + l15; sentence sidx = col/30,
    // word j = col - 30*sidx (sentence boundaries NOT tile-aligned).
    int il[4];
    #pragma unroll
    for (int bb = 0; bb < 4; ++bb) il[bb] = im_len[b0 + bb] - 1;   // in [9, 36]

    // Wave w covers cols [32w, 32w+32) -> at most 2 sentences, base (32w)/30.
    const int sbase = (32 * wave) / 30;
    float part[4][2] = {{0.f, 0.f}, {0.f, 0.f}, {0.f, 0.f}, {0.f, 0.f}};

    #pragma unroll
    for (int t = 0; t < 2; ++t) {
        const int nt = 2 * wave + t;
        if (nt >= NT) continue;                     // wave-uniform
        const int col  = nt * 16 + l15;             // 0..239
        const int sidx = col / 30;                  // per-lane sentence
        const int j    = col - 30 * sidx;           // word index
        const int sl   = s_len[c0 + sidx] - 3;      // valid words, in [5, 30]
        const bool jv  = (j < sl);
        const int s_begin = (nt * 16) / 30;         // wave-uniform
        const int s_end   = (nt * 16 + 15) / 30;

        #pragma unroll
        for (int bb = 0; bb < 4; ++bb) {
            const int ilb = il[bb];
            float m = -3.4e38f;
            #pragma unroll
            for (int mt = 0; mt < MT; ++mt) {
                const int im_lo = (4 * mt) / 9;          // compile-time
                const int im_hi = (4 * mt + 3) / 9;      // compile-time
                const int thr   = 9 * im_hi - 4 * mt;    // q >= thr -> im_hi
                #pragma unroll
                for (int r = 0; r < 4; ++r) {
                    const float v = acc[mt][t][r];
                    const int base = mt * 16 + q * 4 + r;
                    if (im_lo == im_hi) {
                        if (im_lo == bb) {
                            const int i = base - 36 * bb;
                            if (i < ilb) m = fmaxf(m, v);
                        }
                    } else {
                        const bool hi = (q >= thr);
                        if (!hi && im_lo == bb) {
                            const int i = base - 36 * bb;
                            if (i < ilb) m = fmaxf(m, v);
                        } else if (hi && im_hi == bb) {
                            const int i = base - 36 * bb;
                            if (i < ilb) m = fmaxf(m, v);
                        }
                    }
                }
            }
            // combine the 4 row-quads -> full max over image bb's regions
            m = fmaxf(m, __shfl_xor(m, 16, 64));
            m = fmaxf(m, __shfl_xor(m, 32, 64));
            // masked (zeroed) rows participate in the max only when il < 36
            if (ilb < LI) m = fmaxf(m, 0.f);
            const float c = (q == 0 && jv) ? m : 0.f;   // count each col once
            #pragma unroll
            for (int slot = 0; slot < 2; ++slot) {
                const int s = sbase + slot;
                if (s >= s_begin && s <= s_end) {        // wave-uniform
                    float v = (sidx == s) ? c : 0.f;
                    #pragma unroll
                    for (int off = 32; off >= 1; off >>= 1) v += __shfl_xor(v, off, 64);
                    part[bb][slot] += v;
                }
            }
        }
    }

    if (lane == 0) {
        #pragma unroll
        for (int bb = 0; bb < 4; ++bb)
            #pragma unroll
            for (int slot = 0; slot < 2; ++slot)
                sred[wave][bb][slot] = part[bb][slot];
    }
    __syncthreads();
    // 32 score cells: tid -> (bb = tid>>3, s = tid&7); sentence s gathers from
    // the <=2 waves whose 32-col window overlaps cols [30s, 30s+30).
    if (tid < 32) {
        const int bb = tid >> 3, s = tid & 7;
        float v = 0.f;
        #pragma unroll
        for (int w = 0; w < 8; ++w) {
            const int slot = s - (32 * w) / 30;
            if (slot >= 0 && slot < 2) v += sred[w][bb][slot];
        }
        scores[(b0 + bb) * NB + c0 + s] = v;
    }
}

// 64 blocks x 4 waves; wave handles row/col t of the score matrix.
__global__ __launch_bounds__(256) void loss_partial(
    const float* __restrict__ sc, float* __restrict__ partial)
{
    const int wave = threadIdx.x >> 6, lane = threadIdx.x & 63;
    const int t = blockIdx.x * 4 + wave;
    const float dt = sc[t * (NB + 1)];
    float rowmax = 0.f, colmax = 0.f;
    #pragma unroll
    for (int p = 0; p < 4; ++p) {
        const int k = lane + 64 * p;
        const float r = sc[t * NB + k];
        const float c = sc[k * NB + t];
        if (k != t) {
            rowmax = fmaxf(rowmax, 0.2f + r - dt);
            colmax = fmaxf(colmax, 0.2f + c - dt);
        }
    }
    #pragma unroll
    for (int o = 32; o >= 1; o >>= 1) {
        rowmax = fmaxf(rowmax, __shfl_xor(rowmax, o, 64));
        colmax = fmaxf(colmax, __shfl_xor(colmax, o, 64));
    }
    if (lane == 0) partial[t] = fmaxf(rowmax, 0.f) + fmaxf(colmax, 0.f);
}

__global__ __launch_bounds__(256) void loss_final(
    const float* __restrict__ partial, float* __restrict__ out)
{
    const int t = threadIdx.x;
    float v = partial[t];
    __shared__ float red[4];
    #pragma unroll
    for (int o = 32; o >= 1; o >>= 1) v += __shfl_xor(v, o, 64);
    if ((t & 63) == 0) red[t >> 6] = v;
    __syncthreads();
    if (t == 0) out[0] = red[0] + red[1] + red[2] + red[3];
}

extern "C" void kernel_launch(void* const* d_in, const int* in_sizes, int n_in,
                              void* d_out, int out_size, void* d_ws, size_t ws_size,
                              hipStream_t stream) {
    const float* im_set = (const float*)d_in[0];
    const float* s_seq  = (const float*)d_in[1];
    const int*   im_len = (const int*)d_in[2];
    const int*   s_len  = (const int*)d_in[3];
    float* out = (float*)d_out;

    char* ws = (char*)d_ws;
    const size_t imp_bytes = (size_t)NB * LI * DIM * 2;    // 18.9 MB (dense)
    const size_t sp_bytes  = (size_t)NB * LS * DIM * 2;    // 15.7 MB (dense)
    short* imp    = (short*)ws;
    short* sp     = (short*)(ws + imp_bytes);
    float* scores = (float*)(ws + imp_bytes + sp_bytes);   // 256 KB
    float* partial = (float*)(ws + imp_bytes + sp_bytes + (size_t)NB * NB * 4);

    // 256*36 + 256*30 = 16896 rows, one wave each -> 4224 blocks
    normalize_pack<<<4224, 256, 0, stream>>>(im_set, s_seq, imp, sp);

    dim3 grid(NB / 4, NB / 8);
    gemm_scores<<<grid, 512, 0, stream>>>(imp, sp, im_len, s_len, scores);

    loss_partial<<<64, 256, 0, stream>>>(scores, partial);
    loss_final<<<1, 256, 0, stream>>>(partial, out);
}